// Round 8
// baseline (381.033 us; speedup 1.0000x reference)
//
#include <hip/hip_runtime.h>
#include <hip/hip_bf16.h>
#include <math.h>

#define BB 2
#define TT 1024
#define SS 1024
#define DD 1024
#define HH 16
#define DH 64

typedef __attribute__((ext_vector_type(8))) short bf16x8;
typedef __attribute__((ext_vector_type(4))) float f32x4;
typedef unsigned short ushort_t;

#define AS3(p) ((__attribute__((address_space(3))) unsigned int*)(p))
#define AS1(p) ((const __attribute__((address_space(1))) unsigned int*)(p))

__device__ __forceinline__ unsigned short f2b(float f) {
    union { float f; unsigned u; } x; x.f = f;
    unsigned r = x.u + 0x7FFFu + ((x.u >> 16) & 1u);
    return (unsigned short)(r >> 16);
}

// pack 8 f32 -> bf16x8 via v_cvt_pk_bf16_f32 (RNE)
__device__ __forceinline__ bf16x8 pack_bf16x8(float4 a, float4 b) {
    union { unsigned u[4]; bf16x8 v; } r;
    asm("v_cvt_pk_bf16_f32 %0, %1, %2" : "=v"(r.u[0]) : "v"(a.x), "v"(a.y));
    asm("v_cvt_pk_bf16_f32 %0, %1, %2" : "=v"(r.u[1]) : "v"(a.z), "v"(a.w));
    asm("v_cvt_pk_bf16_f32 %0, %1, %2" : "=v"(r.u[2]) : "v"(b.x), "v"(b.y));
    asm("v_cvt_pk_bf16_f32 %0, %1, %2" : "=v"(r.u[3]) : "v"(b.z), "v"(b.w));
    return r.v;
}

// ---------------------------------------------------------------------------
// fp32 -> bf16 conversion: ONE kernel for all 7 tensors.
// ---------------------------------------------------------------------------
__global__ __launch_bounds__(256) void cvt_all(
    const float* __restrict__ q, const float* __restrict__ k, const float* __restrict__ v,
    const float* __restrict__ Wq, const float* __restrict__ Wk,
    const float* __restrict__ Wv, const float* __restrict__ Wo,
    ushort_t* __restrict__ oq, ushort_t* __restrict__ ok, ushort_t* __restrict__ ov,
    ushort_t* __restrict__ oWq, ushort_t* __restrict__ oWk,
    ushort_t* __restrict__ oWv, ushort_t* __restrict__ oWo)
{
    const int y = blockIdx.y;
    if (y >= 3 && blockIdx.x >= 512) return;
    const float* src =
        (y == 0) ? q : (y == 1) ? k : (y == 2) ? v :
        (y == 3) ? Wq : (y == 4) ? Wk : (y == 5) ? Wv : Wo;
    ushort_t* dst =
        (y == 0) ? oq : (y == 1) ? ok : (y == 2) ? ov :
        (y == 3) ? oWq : (y == 4) ? oWk : (y == 5) ? oWv : oWo;
    size_t i = ((size_t)blockIdx.x * 256 + threadIdx.x) * 8;
    float4 v0 = *(const float4*)&src[i];
    float4 v1 = *(const float4*)&src[i + 4];
    uint4 o;
    o.x = f2b(v0.x) | ((unsigned)f2b(v0.y) << 16);
    o.y = f2b(v0.z) | ((unsigned)f2b(v0.w) << 16);
    o.z = f2b(v1.x) | ((unsigned)f2b(v1.y) << 16);
    o.w = f2b(v1.z) | ((unsigned)f2b(v1.w) << 16);
    *(uint4*)&dst[i] = o;
}

// ---------------------------------------------------------------------------
// 128x128 bf16 MFMA GEMM mainloop: BK=64 PING-PONG double buffer.
// ---------------------------------------------------------------------------
__device__ __forceinline__ void gemm128_mainloop(
    const ushort_t* __restrict__ A,
    const ushort_t* __restrict__ Bw,
    int K, ushort_t (*Asm)[128 * 64], ushort_t (*Bsm)[128 * 64],
    f32x4 acc[4][4])
{
    const int tid = threadIdx.x;
    const int wave = tid >> 6, lane = tid & 63;
    const int sr8 = lane >> 3;
    const int gc8 = (lane & 7) ^ sr8;
    const int l15 = lane & 15, q = lane >> 4;
    const int mblk = (wave >> 1) * 64, nblk = (wave & 1) * 64;

#define G128_STAGE(k0_, b_) do {                                               \
        _Pragma("unroll")                                                      \
        for (int o = 0; o < 4; o++) {                                          \
            int r0 = wave * 32 + o * 8;                                        \
            __builtin_amdgcn_global_load_lds(                                  \
                AS1(A + (size_t)(r0 + sr8) * K + (k0_) + gc8 * 8),             \
                AS3(Asm[b_] + r0 * 64), 16, 0, 0);                             \
            __builtin_amdgcn_global_load_lds(                                  \
                AS1(Bw + (size_t)(r0 + sr8) * K + (k0_) + gc8 * 8),            \
                AS3(Bsm[b_] + r0 * 64), 16, 0, 0);                             \
        } } while (0)

#define G128_COMPUTE(b_) do {                                                  \
        _Pragma("unroll")                                                      \
        for (int ks = 0; ks < 2; ks++) {                                       \
            bf16x8 av[4], bv[4];                                               \
            _Pragma("unroll")                                                  \
            for (int mi = 0; mi < 4; mi++) {                                   \
                int r = mblk + mi * 16 + l15;                                  \
                av[mi] = *(const bf16x8*)&Asm[b_][r * 64 + ((ks * 4 + q) ^ (r & 7)) * 8]; \
            }                                                                  \
            _Pragma("unroll")                                                  \
            for (int ni = 0; ni < 4; ni++) {                                   \
                int r = nblk + ni * 16 + l15;                                  \
                bv[ni] = *(const bf16x8*)&Bsm[b_][r * 64 + ((ks * 4 + q) ^ (r & 7)) * 8]; \
            }                                                                  \
            _Pragma("unroll")                                                  \
            for (int mi = 0; mi < 4; mi++)                                     \
                _Pragma("unroll")                                              \
                for (int ni = 0; ni < 4; ni++)                                 \
                    acc[mi][ni] = __builtin_amdgcn_mfma_f32_16x16x32_bf16(     \
                        av[mi], bv[ni], acc[mi][ni], 0, 0, 0);                 \
        } } while (0)

    G128_STAGE(0, 0);
    __syncthreads();

    int buf = 0;
    for (int k0 = 0; k0 < K; k0 += 64) {
        if (k0 + 64 < K) G128_STAGE(k0 + 64, buf ^ 1);
        G128_COMPUTE(buf);
        __syncthreads();
        buf ^= 1;
    }
#undef G128_STAGE
#undef G128_COMPUTE
}

// Fused Q/K/V projections: z<2 -> bf16 (B,T,D); z==2 writes V directly in
// transposed vT layout (B,H,DH,S).
__global__ __launch_bounds__(256) void proj_gemm(
    const ushort_t* __restrict__ qb, const ushort_t* __restrict__ kb, const ushort_t* __restrict__ vb,
    const ushort_t* __restrict__ Wqb, const ushort_t* __restrict__ Wkb, const ushort_t* __restrict__ Wvb,
    const float* __restrict__ bq, const float* __restrict__ bk, const float* __restrict__ bv,
    ushort_t* __restrict__ qh, ushort_t* __restrict__ kh, ushort_t* __restrict__ vT)
{
    __shared__ ushort_t Asm[2][128 * 64];
    __shared__ ushort_t Bsm[2][128 * 64];
    const int z = blockIdx.z;
    const ushort_t* A = (z == 0) ? qb : (z == 1) ? kb : vb;
    const ushort_t* W = (z == 0) ? Wqb : (z == 1) ? Wkb : Wvb;
    const float* bias = (z == 0) ? bq : (z == 1) ? bk : bv;

    const int bm = blockIdx.y * 128, bn = blockIdx.x * 128;
    f32x4 acc[4][4];
    #pragma unroll
    for (int i = 0; i < 4; i++)
        #pragma unroll
        for (int j = 0; j < 4; j++) acc[i][j] = (f32x4)(0.f);

    gemm128_mainloop(A + (size_t)bm * DD, W + (size_t)bn * DD, DD, Asm, Bsm, acc);

    const int lane = threadIdx.x & 63, wave = threadIdx.x >> 6;
    const int mblk = (wave >> 1) * 64, nblk = (wave & 1) * 64;
    const int l15 = lane & 15, q = lane >> 4;

    if (z < 2) {
        ushort_t* Y = (z == 0) ? qh : kh;
        #pragma unroll
        for (int mi = 0; mi < 4; mi++) {
            #pragma unroll
            for (int ni = 0; ni < 4; ni++) {
                int col = bn + nblk + ni * 16 + l15;
                float bcol = bias[col];
                #pragma unroll
                for (int r = 0; r < 4; r++) {
                    int row = bm + mblk + mi * 16 + q * 4 + r;
                    Y[(size_t)row * DD + col] = f2b(acc[mi][ni][r] + bcol);
                }
            }
        }
    } else {
        #pragma unroll
        for (int mi = 0; mi < 4; mi++) {
            int row0 = bm + mblk + mi * 16 + q * 4;
            int b_ = row0 >> 10, s0_ = row0 & 1023;
            #pragma unroll
            for (int ni = 0; ni < 4; ni++) {
                int col = bn + nblk + ni * 16 + l15;
                float bcol = bias[col];
                int h_ = col >> 6, dh_ = col & 63;
                union { unsigned u[2]; } pk;
                pk.u[0] = (unsigned)f2b(acc[mi][ni][0] + bcol)
                        | ((unsigned)f2b(acc[mi][ni][1] + bcol) << 16);
                pk.u[1] = (unsigned)f2b(acc[mi][ni][2] + bcol)
                        | ((unsigned)f2b(acc[mi][ni][3] + bcol) << 16);
                *(uint2*)&vT[((size_t)(b_ * 16 + h_) * 64 + dh_) * SS + s0_] =
                    make_uint2(pk.u[0], pk.u[1]);
            }
        }
    }
}

// Output projection: bf16 in, fp32 out + bias.
__global__ __launch_bounds__(256) void oproj_gemm(
    const ushort_t* __restrict__ A, const ushort_t* __restrict__ W,
    const float* __restrict__ bias, float* __restrict__ Y)
{
    __shared__ ushort_t Asm[2][128 * 64];
    __shared__ ushort_t Bsm[2][128 * 64];
    const int bm = blockIdx.y * 128, bn = blockIdx.x * 128;
    f32x4 acc[4][4];
    #pragma unroll
    for (int i = 0; i < 4; i++)
        #pragma unroll
        for (int j = 0; j < 4; j++) acc[i][j] = (f32x4)(0.f);

    gemm128_mainloop(A + (size_t)bm * DD, W + (size_t)bn * DD, DD, Asm, Bsm, acc);

    const int lane = threadIdx.x & 63, wave = threadIdx.x >> 6;
    const int mblk = (wave >> 1) * 64, nblk = (wave & 1) * 64;
    const int l15 = lane & 15, q = lane >> 4;
    #pragma unroll
    for (int mi = 0; mi < 4; mi++) {
        #pragma unroll
        for (int ni = 0; ni < 4; ni++) {
            int col = bn + nblk + ni * 16 + l15;
            float bcol = bias[col];
            #pragma unroll
            for (int r = 0; r < 4; r++) {
                int row = bm + mblk + mi * 16 + q * 4 + r;
                Y[(size_t)row * DD + col] = acc[mi][ni][r] + bcol;
            }
        }
    }
}

// ---------------------------------------------------------------------------
// FUSED scores + softmax-numerator (m=16 fixed ref) + tanh bias.
// 128x128 causal tiles (36x32 grid, same balance as scores_mfma).
// Bias tile staged into LDS with COALESCED global_load_lds (round-6 fix):
//   - rows 64..127 staged into dedicated 32KB DURING the MFMA
//   - rows 0..63 staged into the dead Q/K 32KB after the MFMA
// Apply phase reads bias from LDS in MFMA layout (no global scalar loads).
// Writes w = exp(clip(s)-16)*sc fp32 + per-row partials (P,W) for av_norm.
// ---------------------------------------------------------------------------
__global__ __launch_bounds__(256) void scores_fused(
    const ushort_t* __restrict__ qh, const ushort_t* __restrict__ kh,
    const float* __restrict__ attn_bias, const float* __restrict__ bias_scale_p,
    float* __restrict__ wout, float* __restrict__ Ppart, float* __restrict__ Wpart)
{
    __shared__ ushort_t SMEM[32768];        // 64 KB total
    ushort_t* Qs = SMEM;                    // 16 KB  (bytes 0..16K)
    ushort_t* Ks = SMEM + 8192;             // 16 KB  (bytes 16K..32K)
    float* BiasF = (float*)SMEM;            // 128x128 fp32 view (64 KB)
                                            //   rows 0..63  = bytes 0..32K (aliases Q/K)
                                            //   rows 64..127 = bytes 32K..64K (dedicated)
    __shared__ float pPs[128][2];
    __shared__ float pWs[128][2];

    int idx = blockIdx.x, ti = 0;
    while (idx >= ti + 1) { idx -= ti + 1; ti++; }
    const int si = idx;
    const int bh = blockIdx.y;
    const int b = bh >> 4, h = bh & 15;
    const int t0 = ti * 128, s0 = si * 128;

    const int tid = threadIdx.x;
    const int wave = tid >> 6, lane = tid & 63;
    const int sr8 = lane >> 3;
    const int gc8 = (lane & 7) ^ sr8;

    // ---- stage Q, K ----
    #pragma unroll
    for (int o = 0; o < 4; o++) {
        int r0 = (wave * 4 + o) * 8;
        int r = r0 + sr8;
        __builtin_amdgcn_global_load_lds(
            AS1(qh + ((size_t)(b * TT + t0 + r) * HH + h) * DH + gc8 * 8),
            AS3(Qs + r0 * 64), 16, 0, 0);
        __builtin_amdgcn_global_load_lds(
            AS1(kh + ((size_t)(b * SS + s0 + r) * HH + h) * DH + gc8 * 8),
            AS3(Ks + r0 * 64), 16, 0, 0);
    }
    __syncthreads();

    // ---- issue bias rows 64..127 staging (lands during MFMA) ----
    // per instr: 2 rows (512B each), 64 lanes x 16B = 1KB, dest linear.
    #pragma unroll
    for (int o = 0; o < 8; o++) {
        int tl = 64 + wave * 16 + o * 2;                 // wave-uniform row base
        __builtin_amdgcn_global_load_lds(
            AS1(attn_bias + ((size_t)(bh * TT + t0 + tl + (lane >> 5)) * SS
                             + s0 + (lane & 31) * 4)),
            AS3(BiasF + tl * 128), 16, 0, 0);
    }

    // ---- MFMA (identical to scores_mfma) ----
    const int l15 = lane & 15, q = lane >> 4;
    const int tblk = (wave >> 1) * 64, sblk = (wave & 1) * 64;
    f32x4 acc[4][4];
    #pragma unroll
    for (int i = 0; i < 4; i++)
        #pragma unroll
        for (int j = 0; j < 4; j++) acc[i][j] = (f32x4)(0.f);

    #pragma unroll
    for (int ks = 0; ks < 2; ks++) {
        bf16x8 av[4], bv[4];
        #pragma unroll
        for (int mi = 0; mi < 4; mi++) {
            int r = tblk + mi * 16 + l15;
            av[mi] = *(const bf16x8*)&Qs[r * 64 + ((ks * 4 + q) ^ (r & 7)) * 8];
        }
        #pragma unroll
        for (int ni = 0; ni < 4; ni++) {
            int r = sblk + ni * 16 + l15;
            bv[ni] = *(const bf16x8*)&Ks[r * 64 + ((ks * 4 + q) ^ (r & 7)) * 8];
        }
        #pragma unroll
        for (int mi = 0; mi < 4; mi++)
            #pragma unroll
            for (int ni = 0; ni < 4; ni++)
                acc[mi][ni] = __builtin_amdgcn_mfma_f32_16x16x32_bf16(av[mi], bv[ni], acc[mi][ni], 0, 0, 0);
    }
    __syncthreads();   // MFMA LDS reads done; bias rows 64..127 drained

    // ---- stage bias rows 0..63 into the dead Q/K region ----
    #pragma unroll
    for (int o = 0; o < 8; o++) {
        int tl = wave * 16 + o * 2;
        __builtin_amdgcn_global_load_lds(
            AS1(attn_bias + ((size_t)(bh * TT + t0 + tl + (lane >> 5)) * SS
                             + s0 + (lane & 31) * 4)),
            AS3(BiasF + tl * 128), 16, 0, 0);
    }
    __syncthreads();

    // ---- apply: p, bias scale, w write, partial sums ----
    const float bscale = bias_scale_p[0];
    float rowP[4][4], rowW[4][4];
    #pragma unroll
    for (int mi = 0; mi < 4; mi++)
        #pragma unroll
        for (int r = 0; r < 4; r++) { rowP[mi][r] = 0.f; rowW[mi][r] = 0.f; }

    #pragma unroll
    for (int mi = 0; mi < 4; mi++) {
        #pragma unroll
        for (int ni = 0; ni < 4; ni++) {
            int s_l = sblk + ni * 16 + l15;
            int scol = s0 + s_l;
            #pragma unroll
            for (int r = 0; r < 4; r++) {
                int t_l = tblk + mi * 16 + q * 4 + r;
                int t = t0 + t_l;
                float s = fminf(fmaxf(acc[mi][ni][r] * 0.125f, -80.f), 80.f);
                float p = (scol <= t) ? __expf(s - 16.f) : 0.f;
                float bvv = BiasF[t_l * 128 + s_l];
                float e = __expf(-2.f * fabsf(bvv));
                float th = copysignf((1.f - e) / (1.f + e), bvv);
                float sc = fmaxf(1.f + bscale * th, 1e-9f);
                float w = p * sc;
                wout[((size_t)bh * TT + t) * SS + scol] = w;
                rowP[mi][r] += p;
                rowW[mi][r] += w;
            }
        }
    }

    // reduce over the 16 l15 lanes (same row group)
    #pragma unroll
    for (int off = 1; off < 16; off <<= 1) {
        #pragma unroll
        for (int mi = 0; mi < 4; mi++)
            #pragma unroll
            for (int r = 0; r < 4; r++) {
                rowP[mi][r] += __shfl_xor(rowP[mi][r], off);
                rowW[mi][r] += __shfl_xor(rowW[mi][r], off);
            }
    }
    if (l15 == 0) {
        #pragma unroll
        for (int mi = 0; mi < 4; mi++)
            #pragma unroll
            for (int r = 0; r < 4; r++) {
                int row = tblk + mi * 16 + q * 4 + r;
                pPs[row][wave & 1] = rowP[mi][r];
                pWs[row][wave & 1] = rowW[mi][r];
            }
    }
    __syncthreads();
    if (tid < 128) {
        float P2 = pPs[tid][0] + pPs[tid][1];
        float W2 = pWs[tid][0] + pWs[tid][1];
        size_t o = ((size_t)bh * TT + t0 + tid) * 8 + si;
        Ppart[o] = P2;
        Wpart[o] = W2;
    }
}

// ---------------------------------------------------------------------------
// AV + attn normalization writeout (round-6 proven). 64t x 64dh per block.
// inv[t] from partials; per s-tile: stage V (bf16) + w (fp32) via
// global_load_lds; A-frags direct from global (L2-hot); writeback attn = w*inv
// coalesced from Wsm. Zero tiles up front. Heavy blocks first. LDS 48KB.
// ---------------------------------------------------------------------------
__global__ __launch_bounds__(256) void av_norm_mfma(
    const float* __restrict__ w, const ushort_t* __restrict__ vT,
    const float* __restrict__ Ppart, const float* __restrict__ Wpart,
    float* __restrict__ attn, ushort_t* __restrict__ ao)
{
    __shared__ ushort_t Vsm[2][64 * 64];   // 16 KB
    __shared__ float Wsm[2][64 * 64];      // 32 KB
    __shared__ float sInv[64];

    const int tb = (int)gridDim.x - 1 - (int)blockIdx.x;   // heavy first
    const int bh = blockIdx.y;
    const int b = bh >> 4, h = bh & 15;
    const int t0 = tb * 64;
    const int nst = tb + 1;

    const int tid = threadIdx.x;
    const int wave = tid >> 6, lane = tid & 63;
    const int sr8 = lane >> 3, gc8 = (lane & 7) ^ sr8;
    const int l15 = lane & 15, q = lane >> 4;

    if (tid < 64) {
        int t = t0 + tid;
        int n2 = (t >> 7) + 1;
        const float* pp = Ppart + ((size_t)bh * TT + t) * 8;
        const float* ww = Wpart + ((size_t)bh * TT + t) * 8;
        float P = 0.f, W = 0.f;
        for (int j = 0; j < n2; j++) { P += pp[j]; W += ww[j]; }
        sInv[tid] = 1.f / (W + 1e-9f * P);
    }

    float* aout_base = attn + ((size_t)bh * TT + t0) * SS;

    {
        float4 z = make_float4(0.f, 0.f, 0.f, 0.f);
        const int zr = tid >> 4, zc = (tid & 15) * 4;
        for (int si = nst; si < SS / 64; si++)
            #pragma unroll
            for (int kk = 0; kk < 4; kk++)
                *(float4*)&aout_base[(size_t)(zr + kk * 16) * SS + si * 64 + zc] = z;
    }

    const float* arow = w + ((size_t)bh * TT + t0 + wave * 16 + l15) * SS + q * 8;
    const ushort_t* vbase = vT + (size_t)bh * DH * SS;
    const float* wtile_base = w + ((size_t)bh * TT + t0) * SS;

    f32x4 acc[4];
    #pragma unroll
    for (int i = 0; i < 4; i++) acc[i] = (f32x4)(0.f);

#define STAGE_V(sidx, bb) do {                                                \
        _Pragma("unroll")                                                     \
        for (int o = 0; o < 2; o++) {                                         \
            int r0 = wave * 16 + o * 8;                                       \
            __builtin_amdgcn_global_load_lds(                                 \
                AS1(vbase + (size_t)(r0 + sr8) * SS + (sidx) * 64 + gc8 * 8), \
                AS3(&Vsm[bb][r0 * 64]), 16, 0, 0);                            \
        } } while (0)

#define STAGE_W(sidx, bb) do {                                                \
        _Pragma("unroll")                                                     \
        for (int i_ = 0; i_ < 4; i_++) {                                      \
            int row_ = wave * 16 + i_ * 4 + (lane >> 4);                      \
            __builtin_amdgcn_global_load_lds(                                 \
                AS1(wtile_base + (size_t)row_ * SS + (sidx) * 64 + (lane & 15) * 4), \
                AS3(&Wsm[bb][wave * 1024 + i_ * 256]), 16, 0, 0);             \
        } } while (0)

#define LOAD_A(sidx, dst) do {                                                \
        const float* p_ = arow + (sidx) * 64;                                 \
        dst[0] = *(const float4*)(p_);                                        \
        dst[1] = *(const float4*)(p_ + 4);                                    \
        dst[2] = *(const float4*)(p_ + 32);                                   \
        dst[3] = *(const float4*)(p_ + 36); } while (0)

#define COMPUTE(bb, ax) do {                                                  \
        bf16x8 af0 = pack_bf16x8(ax[0], ax[1]);                               \
        bf16x8 af1 = pack_bf16x8(ax[2], ax[3]);                               \
        _Pragma("unroll")                                                     \
        for (int ni = 0; ni < 4; ni++) {                                      \
            int rv = ni * 16 + l15;                                           \
            bf16x8 b0 = *(const bf16x8*)&Vsm[bb][rv * 64 + ((q) ^ (rv & 7)) * 8];       \
            bf16x8 b1 = *(const bf16x8*)&Vsm[bb][rv * 64 + ((4 + q) ^ (rv & 7)) * 8];   \
            acc[ni] = __builtin_amdgcn_mfma_f32_16x16x32_bf16(af0, b0, acc[ni], 0, 0, 0);\
            acc[ni] = __builtin_amdgcn_mfma_f32_16x16x32_bf16(af1, b1, acc[ni], 0, 0, 0);\
        } } while (0)

#define WRITEBACK(bb, sidx) do {                                              \
        const int wc_ = (tid & 15) * 4;                                       \
        _Pragma("unroll")                                                     \
        for (int kk = 0; kk < 4; kk++) {                                      \
            int row_ = (tid >> 4) + kk * 16;                                  \
            float4 vv = *(const float4*)&Wsm[bb][row_ * 64 + wc_];            \
            float iv_ = sInv[row_];                                           \
            vv.x *= iv_; vv.y *= iv_; vv.z *= iv_; vv.w *= iv_;               \
            *(float4*)&aout_base[(size_t)row_ * SS + (sidx) * 64 + wc_] = vv; \
        } } while (0)

    float4 aA[4], aB[4];
    STAGE_V(0, 0);
    STAGE_W(0, 0);
    LOAD_A(0, aA);
    __syncthreads();   // drains stage(0); also publishes sInv

    int st = 0;
    while (true) {
        if (st + 1 < nst) { STAGE_V(st + 1, 1); STAGE_W(st + 1, 1); LOAD_A(st + 1, aB); }
        COMPUTE(0, aA);
        WRITEBACK(0, st);
        __syncthreads();
        if (++st == nst) break;
        if (st + 1 < nst) { STAGE_V(st + 1, 0); STAGE_W(st + 1, 0); LOAD_A(st + 1, aA); }
        COMPUTE(1, aB);
        WRITEBACK(1, st);
        __syncthreads();
        if (++st == nst) break;
    }
#undef STAGE_V
#undef STAGE_W
#undef LOAD_A
#undef COMPUTE
#undef WRITEBACK

    #pragma unroll
    for (int ni = 0; ni < 4; ni++) {
        int dh = ni * 16 + l15;
        #pragma unroll
        for (int r = 0; r < 4; r++) {
            int trow = wave * 16 + q * 4 + r;
            float iv = sInv[trow];
            int t = t0 + trow;
            ao[(size_t)(b * TT + t) * DD + h * DH + dh] = f2b(acc[ni][r] * iv);
        }
    }
}

// ---------------------------------------------------------------------------
extern "C" void kernel_launch(void* const* d_in, const int* in_sizes, int n_in,
                              void* d_out, int out_size, void* d_ws, size_t ws_size,
                              hipStream_t stream)
{
    const float* q   = (const float*)d_in[0];
    const float* k   = (const float*)d_in[1];
    const float* v   = (const float*)d_in[2];
    const float* attn_bias = (const float*)d_in[4];
    const float* Wq = (const float*)d_in[5];
    const float* bq = (const float*)d_in[6];
    const float* Wk = (const float*)d_in[7];
    const float* bk = (const float*)d_in[8];
    const float* Wv = (const float*)d_in[9];
    const float* bv = (const float*)d_in[10];
    const float* Wo = (const float*)d_in[11];
    const float* bo = (const float*)d_in[12];
    const float* bscale = (const float*)d_in[13];

    // ws layout (32 MB total):
    char* base = (char*)d_ws;
    ushort_t* qb  = (ushort_t*)(base + (0ull << 20));   // 4 MB
    ushort_t* kb  = (ushort_t*)(base + (4ull << 20));   // 4 MB, later ao
    ushort_t* vb  = (ushort_t*)(base + (8ull << 20));   // 4 MB, later P/W parts
    ushort_t* Wqb = (ushort_t*)(base + (12ull << 20));  // 2 MB
    ushort_t* Wkb = (ushort_t*)(base + (14ull << 20));  // 2 MB
    ushort_t* Wvb = (ushort_t*)(base + (16ull << 20));  // 2 MB
    ushort_t* Wob = (ushort_t*)(base + (18ull << 20));  // 2 MB
    ushort_t* qhb = (ushort_t*)(base + (20ull << 20));  // 4 MB
    ushort_t* khb = (ushort_t*)(base + (24ull << 20));  // 4 MB
    ushort_t* vT  = (ushort_t*)(base + (28ull << 20));  // 4 MB (written by proj z==2)
    ushort_t* aob = kb;                                 // alias: kb dead after proj
    float* PpartB = (float*)(base + (8ull << 20));      // 1 MB (vb dead after proj)
    float* WpartB = (float*)(base + (9ull << 20));      // 1 MB

    float* out  = (float*)d_out;
    float* attn = out + (size_t)BB * TT * DD;

    cvt_all<<<dim3(1024, 7), 256, 0, stream>>>(q, k, v, Wq, Wk, Wv, Wo,
                                               qb, kb, vb, Wqb, Wkb, Wvb, Wob);
    proj_gemm<<<dim3(8, 16, 3), 256, 0, stream>>>(qb, kb, vb, Wqb, Wkb, Wvb,
                                                  bq, bk, bv, qhb, khb, vT);
    scores_fused<<<dim3(36, 32), 256, 0, stream>>>(qhb, khb, attn_bias, bscale,
                                                   attn, PpartB, WpartB);
    av_norm_mfma<<<dim3(16, 32), 256, 0, stream>>>(attn, vT, PpartB, WpartB,
                                                   attn, aob);
    oproj_gemm<<<dim3(8, 16), 256, 0, stream>>>(aob, Wob, bo, out);
}